// Round 4
// baseline (241.395 us; speedup 1.0000x reference)
//
#include <hip/hip_runtime.h>

// Problem constants
#define B_    4096
#define T_    32
#define OUT_  8
#define BTILE 32
#define NBLK  (B_ / BTILE)   // 128 main-kernel blocks

typedef _Float16 f16;
typedef _Float16 f16x4 __attribute__((ext_vector_type(4)));
typedef _Float16 f16x8 __attribute__((ext_vector_type(8)));
typedef float    f32x4 __attribute__((ext_vector_type(4)));

// ---- workspace layout (bytes). Total ~25.2 MB ----
// [0, 8448): f32 weights (WA 1024, WO 1024, biasA 16 @f32idx 2048, biasB 16 @f32idx 2112)
#define WS_AENC 16384u                    // [B*T][16] f16 = 4 MB
#define WS_OENC (WS_AENC + 4194304u)      // 4 MB
#define WS_H    (WS_OENC + 4194304u)      // f16 relaid H: 16 MB
// H granule (1 KB) per (t, p, s, nf): addr = (((t*32+p)*8+s)*2+nf)*1024
// granule byte (g4*16+m16)*16 + slot*2 ; slot h*4+r = Ht[p][j=2s+h][kk=g4*4+r][l=nf*16+m16] * (1/8)

// ------------------- prep 1: fuse encoder weights -------------------
__global__ void k_fuse_w(const float* __restrict__ Wa0, const float* __restrict__ ba0,
                         const float* __restrict__ Wa1, const float* __restrict__ ba1,
                         const float* __restrict__ Wo0, const float* __restrict__ bo0,
                         const float* __restrict__ Wo1, const float* __restrict__ bo1,
                         float* __restrict__ ws) {
  const int tid = threadIdx.x;  // 256 threads, 1 block
  for (int idx = tid; idx < 1024; idx += 256) {
    const int d = idx >> 4, j = idx & 15;
    float s = 0.f, s2 = 0.f;
    for (int h = 0; h < 128; ++h) {
      s  += Wa0[d * 128 + h] * Wa1[h * 16 + j];
      s2 += Wo0[d * 128 + h] * Wo1[h * 16 + j];
    }
    ws[idx] = s;
    ws[1024 + idx] = s2;
  }
  if (tid < 16) {
    float s = 0.f, s2 = 0.f;
    for (int h = 0; h < 128; ++h) {
      s  += ba0[h] * Wa1[h * 16 + tid];
      s2 += bo0[h] * Wo1[h * 16 + tid];
    }
    ws[2048 + tid] = s + ba1[tid];
    ws[2112 + tid] = s2 + bo1[tid];
  }
}

// ------------------- prep 2: MFMA encoder (f16 in, f32 acc) -------------------
__global__ void k_encode(const float* __restrict__ action, const float* __restrict__ obs,
                         const float* __restrict__ ws,
                         f16* __restrict__ aenc, f16* __restrict__ oenc) {
  const int tid = threadIdx.x;
  const int lane = tid & 63;
  const int v = tid >> 6;
  const int m16 = lane & 15, g4 = lane >> 4;
  const int bt0 = blockIdx.x * 64 + v * 16;

  f16x8 wbA[2], wbB[2];
  #pragma unroll
  for (int ks = 0; ks < 2; ++ks)
    #pragma unroll
    for (int h = 0; h < 2; ++h)
      #pragma unroll
      for (int r = 0; r < 4; ++r) {
        const int d = ks * 32 + h * 16 + g4 * 4 + r;
        wbA[ks][h * 4 + r] = (f16)ws[d * 16 + m16];
        wbB[ks][h * 4 + r] = (f16)ws[1024 + d * 16 + m16];
      }
  const float biasA = ws[2048 + m16], biasB = ws[2112 + m16];
  f32x4 accA = {biasA, biasA, biasA, biasA};
  f32x4 accB = {biasB, biasB, biasB, biasB};

  const float* ar = action + (size_t)(bt0 + m16) * 64;
  const float* br = obs    + (size_t)(bt0 + m16) * 64;
  #pragma unroll
  for (int ks = 0; ks < 2; ++ks) {
    f16x8 aa, oo;
    #pragma unroll
    for (int h = 0; h < 2; ++h) {
      const f32x4 a4 = *(const f32x4*)(ar + ks * 32 + h * 16 + g4 * 4);
      const f32x4 o4 = *(const f32x4*)(br + ks * 32 + h * 16 + g4 * 4);
      #pragma unroll
      for (int r = 0; r < 4; ++r) { aa[h * 4 + r] = (f16)a4[r]; oo[h * 4 + r] = (f16)o4[r]; }
    }
    accA = __builtin_amdgcn_mfma_f32_16x16x32_f16(aa, wbA[ks], accA, 0, 0, 0);
    accB = __builtin_amdgcn_mfma_f32_16x16x32_f16(oo, wbB[ks], accB, 0, 0, 0);
  }
  #pragma unroll
  for (int r = 0; r < 4; ++r) {
    aenc[(size_t)(bt0 + g4 * 4 + r) * 16 + m16] = (f16)accA[r];
    oenc[(size_t)(bt0 + g4 * 4 + r) * 16 + m16] = (f16)accB[r];
  }
}

// ------------------- prep 3: relayout H -> f16 granules, scaled by 1/8 -------------------
__global__ void k_hprep(const float* __restrict__ Hf, const float* __restrict__ Hm,
                        const float* __restrict__ Hl, f16* __restrict__ hdst) {
  const int x = blockIdx.x * 256 + threadIdx.x;     // < 1048576
  const int lane = x & 63;
  const int gid = x >> 6;
  const int nf = gid & 1, s = (gid >> 1) & 7, p = (gid >> 4) & 31, t = gid >> 9;
  const int m16 = lane & 15, g4 = lane >> 4;
  const int l = nf * 16 + m16;
  f16x8 gout;
  #pragma unroll
  for (int h = 0; h < 2; ++h) {
    const int j = 2 * s + h;
    #pragma unroll
    for (int r = 0; r < 4; ++r) {
      const int kk = g4 * 4 + r;
      float vsrc;
      if (t == 0)       vsrc = (p == 0) ? Hf[(j * 16 + kk) * 32 + l] : 0.f;
      else if (t == 31) vsrc = (l < 8) ? Hl[((p * 16 + j) * 16 + kk) * 8 + l] : 0.f;
      else              vsrc = Hm[((((size_t)(t - 1) * 32 + p) * 16 + j) * 16 + kk) * 32 + l];
      gout[h * 4 + r] = (f16)(vsrc * 0.125f);
    }
  }
  *(f16x8*)((char*)hdst + (size_t)x * 16) = gout;
}

// ------------------- main fused kernel -------------------
// 128 blocks x 512 threads (8 waves, 2/SIMD on 128 CUs). Wave w owns p in [4w, 4w+4).
// H streamed global->VGPR via two named quarter-t buffers (16 granules = 64 VGPR each);
// compute/issue interleave with anti-dependences so the allocator cannot collapse the
// pipeline. amdgpu_waves_per_eu(2,2) frees the allocator to hold ~200 VGPRs.
__launch_bounds__(512)
__attribute__((amdgpu_waves_per_eu(2, 2)))
__global__ void k_main(const f16* __restrict__ aenc, const f16* __restrict__ oenc,
                       const char* __restrict__ hws, float* __restrict__ out) {
  __shared__ __align__(16) float cpart[8][32][40];  // [wave][l-col][b-row], pad 40
  __shared__ float cfull[32][40];                   // [p][b]

  const int tid  = threadIdx.x;
  const int lane = tid & 63;
  const int w    = tid >> 6;       // 0..7
  const int m16  = lane & 15;
  const int g4   = lane >> 4;      // 0..3
  const int b0   = blockIdx.x * BTILE;

  // init chain state: c[p][b] = (p == 0)
  #pragma unroll
  for (int rep = 0; rep < 2; ++rep) {
    const int e = tid + rep * 512;
    cfull[e >> 5][e & 31] = ((e >> 5) == 0) ? 1.f : 0.f;
  }

  // per-wave granule base: p = w*4 + pp
  const char* hl = hws + (size_t)(w * 4) * 16384 + (size_t)lane * 16;

  f16x8 bufA[16], bufB[16];

#define QLOAD(X, tt, pp) do {                                                  \
    const char* qa_ = hl + (size_t)(tt) * 524288 + (size_t)(pp) * 16384;       \
    _Pragma("unroll")                                                          \
    for (int s_ = 0; s_ < 8; ++s_) {                                           \
      X[2 * s_]     = *(const f16x8*)(qa_ + s_ * 2048);                        \
      X[2 * s_ + 1] = *(const f16x8*)(qa_ + s_ * 2048 + 1024);                 \
    }                                                                          \
  } while (0)

#define QCOMP(X, pp) do {                                                      \
    const f16 c0_ = cfh0[pp], c1_ = cfh1[pp];                                  \
    _Pragma("unroll")                                                          \
    for (int s_ = 0; s_ < 8; ++s_) {                                           \
      const f16 a00 = c0_ * ((s_ < 4) ? al0[2 * s_]     : ah0[2 * s_ - 8]);    \
      const f16 a01 = c0_ * ((s_ < 4) ? al0[2 * s_ + 1] : ah0[2 * s_ - 7]);    \
      const f16 a10 = c1_ * ((s_ < 4) ? al1[2 * s_]     : ah1[2 * s_ - 8]);    \
      const f16 a11 = c1_ * ((s_ < 4) ? al1[2 * s_ + 1] : ah1[2 * s_ - 7]);    \
      f16x8 af0, af1;                                                          \
      _Pragma("unroll")                                                        \
      for (int r_ = 0; r_ < 4; ++r_) {                                         \
        af0[r_] = a00 * ov0[r_]; af0[4 + r_] = a01 * ov0[r_];                  \
        af1[r_] = a10 * ov1[r_]; af1[4 + r_] = a11 * ov1[r_];                  \
      }                                                                        \
      acc00 = __builtin_amdgcn_mfma_f32_16x16x32_f16(af0, X[2 * s_],     acc00, 0, 0, 0); \
      acc01 = __builtin_amdgcn_mfma_f32_16x16x32_f16(af0, X[2 * s_ + 1], acc01, 0, 0, 0); \
      acc10 = __builtin_amdgcn_mfma_f32_16x16x32_f16(af1, X[2 * s_],     acc10, 0, 0, 0); \
      acc11 = __builtin_amdgcn_mfma_f32_16x16x32_f16(af1, X[2 * s_ + 1], acc11, 0, 0, 0); \
    }                                                                          \
  } while (0)

  // enc regs (current t)
  f16x8 al0, ah0, al1, ah1;
  f16x4 ov0, ov1;
  {
    const f16* ap0 = aenc + ((size_t)(b0 + m16) * T_ + 0) * 16;
    const f16* ap1 = aenc + ((size_t)(b0 + 16 + m16) * T_ + 0) * 16;
    al0 = *(const f16x8*)ap0; ah0 = *(const f16x8*)(ap0 + 8);
    al1 = *(const f16x8*)ap1; ah1 = *(const f16x8*)(ap1 + 8);
    ov0 = *(const f16x4*)(oenc + ((size_t)(b0 + m16) * T_ + 0) * 16 + g4 * 4);
    ov1 = *(const f16x4*)(oenc + ((size_t)(b0 + 16 + m16) * T_ + 0) * 16 + g4 * 4);
  }
  QLOAD(bufA, 0, 0);
  QLOAD(bufB, 0, 1);
  __syncthreads();

  #pragma clang loop unroll(disable)
  for (int t = 0; t < T_; ++t) {
    const int tn = (t < 31) ? t + 1 : 31;

    // chain-state reads: c[b = mf*16+m16][p = w*4+pp], converted to f16
    f16 cfh0[4], cfh1[4];
    #pragma unroll
    for (int pp = 0; pp < 4; ++pp) {
      cfh0[pp] = (f16)cfull[w * 4 + pp][m16];
      cfh1[pp] = (f16)cfull[w * 4 + pp][16 + m16];
    }

    f32x4 acc00 = {0.f, 0.f, 0.f, 0.f}, acc01 = {0.f, 0.f, 0.f, 0.f};
    f32x4 acc10 = {0.f, 0.f, 0.f, 0.f}, acc11 = {0.f, 0.f, 0.f, 0.f};

    // ---- interleaved compute/issue pipeline over the 4 p-quarters ----
    QCOMP(bufA, 0);
    QLOAD(bufA, t, 2);
    QCOMP(bufB, 1);
    QLOAD(bufB, t, 3);
    QCOMP(bufA, 2);
    QLOAD(bufA, tn, 0);
    QCOMP(bufB, 3);
    QLOAD(bufB, tn, 1);

    // stage next-t enc inputs (anti-dep: issued after last QCOMP consumed cur regs)
    {
      const f16* ap0 = aenc + ((size_t)(b0 + m16) * T_ + tn) * 16;
      const f16* ap1 = aenc + ((size_t)(b0 + 16 + m16) * T_ + tn) * 16;
      al0 = *(const f16x8*)ap0; ah0 = *(const f16x8*)(ap0 + 8);
      al1 = *(const f16x8*)ap1; ah1 = *(const f16x8*)(ap1 + 8);
      ov0 = *(const f16x4*)(oenc + ((size_t)(b0 + m16) * T_ + tn) * 16 + g4 * 4);
      ov1 = *(const f16x4*)(oenc + ((size_t)(b0 + 16 + m16) * T_ + tn) * 16 + g4 * 4);
    }

    // ---- chain phase: write partials, reduce across waves ----
    // D: col = m16 (= l within nf) ; rows = mf*16 + g4*4 + r
    *(f32x4*)&cpart[w][m16][g4 * 4]           = acc00;
    *(f32x4*)&cpart[w][16 + m16][g4 * 4]      = acc01;
    *(f32x4*)&cpart[w][m16][16 + g4 * 4]      = acc10;
    *(f32x4*)&cpart[w][16 + m16][16 + g4 * 4] = acc11;
    __syncthreads();
    #pragma unroll
    for (int rep = 0; rep < 2; ++rep) {
      const int e = tid + rep * 512;
      const int p = e >> 5, bb = e & 31;
      float ssum = 0.f;
      #pragma unroll
      for (int ww = 0; ww < 8; ++ww) ssum += cpart[ww][p][bb];
      if (t < 31) cfull[p][bb] = ssum;
      else if (p < 8) out[(size_t)(b0 + bb) * 8 + p] = ssum * 0x1p96f;  // undo 8^-32 scaling
    }
    __syncthreads();
  }
#undef QLOAD
#undef QCOMP
}

extern "C" void kernel_launch(void* const* d_in, const int* in_sizes, int n_in,
                              void* d_out, int out_size, void* d_ws, size_t ws_size,
                              hipStream_t stream) {
  (void)in_sizes; (void)n_in; (void)out_size; (void)ws_size;
  const float* action = (const float*)d_in[0];
  const float* obs    = (const float*)d_in[1];
  const float* Wa0 = (const float*)d_in[2];
  const float* ba0 = (const float*)d_in[3];
  const float* Wa1 = (const float*)d_in[4];
  const float* ba1 = (const float*)d_in[5];
  const float* Wo0 = (const float*)d_in[6];
  const float* bo0 = (const float*)d_in[7];
  const float* Wo1 = (const float*)d_in[8];
  const float* bo1 = (const float*)d_in[9];
  const float* Hf  = (const float*)d_in[10];
  const float* Hm  = (const float*)d_in[11];
  const float* Hl  = (const float*)d_in[12];
  char*  ws  = (char*)d_ws;
  float* out = (float*)d_out;

  k_fuse_w<<<1, 256, 0, stream>>>(Wa0, ba0, Wa1, ba1, Wo0, bo0, Wo1, bo1, (float*)ws);
  k_encode<<<(B_ * T_) / 64, 256, 0, stream>>>(action, obs, (const float*)ws,
                                               (f16*)(ws + WS_AENC), (f16*)(ws + WS_OENC));
  k_hprep<<<4096, 256, 0, stream>>>(Hf, Hm, Hl, (f16*)(ws + WS_H));
  k_main<<<NBLK, 512, 0, stream>>>((const f16*)(ws + WS_AENC), (const f16*)(ws + WS_OENC),
                                   (const char*)(ws + WS_H), out);
}